// Round 1
// 263.847 us; speedup vs baseline: 1.0453x; 1.0453x over previous
//
#include <hip/hip_runtime.h>
#include <math.h>

#define NB 256          // batches
#define NPT 8192        // points per batch
#define SPLITS 4        // blocks per batch for the streaming passes
#define CHUNK (NPT / SPLITS)
#define THREADS 256
#define CLAMPV 10.0f

// ---------------------------------------------------------------------------
// Pass 1: per (batch, split) partial sums: sum(pred)[3], sum(true)[3],
//         M[i][j] = sum pred_i * true_j [9]  -> stats[blk*16 + 0..14]
// Vectorized: 3x float4 per 4 points (AoS float3 pattern).
// ---------------------------------------------------------------------------
__global__ __launch_bounds__(THREADS) void cov_kernel(
    const float* __restrict__ pred, const float* __restrict__ tru,
    float* __restrict__ stats)
{
    const int blk = blockIdx.x;
    const int b  = blk >> 2;   // / SPLITS
    const int sp = blk & 3;    // % SPLITS
    const float4* __restrict__ P4 =
        (const float4*)(pred + ((size_t)b * NPT + (size_t)sp * CHUNK) * 3);
    const float4* __restrict__ T4 =
        (const float4*)(tru  + ((size_t)b * NPT + (size_t)sp * CHUNK) * 3);

    float acc[15];
#pragma unroll
    for (int i = 0; i < 15; ++i) acc[i] = 0.f;

#define COVACC(px,py,pz,tx,ty,tz)                                   \
    do {                                                            \
        acc[0] += (px); acc[1] += (py); acc[2] += (pz);             \
        acc[3] += (tx); acc[4] += (ty); acc[5] += (tz);             \
        acc[6]  += (px)*(tx); acc[7]  += (px)*(ty); acc[8]  += (px)*(tz); \
        acc[9]  += (py)*(tx); acc[10] += (py)*(ty); acc[11] += (py)*(tz); \
        acc[12] += (pz)*(tx); acc[13] += (pz)*(ty); acc[14] += (pz)*(tz); \
    } while (0)

    for (int g = threadIdx.x; g < CHUNK / 4; g += THREADS) {
        const float4 pa = P4[3*g+0], pb = P4[3*g+1], pc = P4[3*g+2];
        const float4 ta = T4[3*g+0], tb = T4[3*g+1], tc = T4[3*g+2];
        COVACC(pa.x, pa.y, pa.z,  ta.x, ta.y, ta.z);
        COVACC(pa.w, pb.x, pb.y,  ta.w, tb.x, tb.y);
        COVACC(pb.z, pb.w, pc.x,  tb.z, tb.w, tc.x);
        COVACC(pc.y, pc.z, pc.w,  tc.y, tc.z, tc.w);
    }
#undef COVACC

#pragma unroll
    for (int i = 0; i < 15; ++i)
        for (int off = 32; off > 0; off >>= 1)
            acc[i] += __shfl_down(acc[i], off, 64);

    __shared__ float smem[THREADS/64][15];
    const int wave = threadIdx.x >> 6, lane = threadIdx.x & 63;
    if (lane == 0) {
#pragma unroll
        for (int i = 0; i < 15; ++i) smem[wave][i] = acc[i];
    }
    __syncthreads();
    if (threadIdx.x < 15) {
        float s = 0.f;
#pragma unroll
        for (int w = 0; w < THREADS/64; ++w) s += smem[w][threadIdx.x];
        stats[(size_t)blk * 16 + threadIdx.x] = s;
    }
}

// ---------------------------------------------------------------------------
// Pass 2: one thread per batch. Fully register-resident fp64 Jacobi SVD of
// the 3x3 covariance via eig(H^T H). All matrix elements are NAMED SCALARS
// (no runtime-indexed arrays -> no scratch). Branchless rotations, 7 sweeps.
// Kabsch R = V U^T with det fix folded as a sign on the argmin-eig column.
// Writes RT[b*12] = R row-major (9) + t (3) as fp32.
// ---------------------------------------------------------------------------
__device__ __forceinline__ void jrot(
    double& app, double& aqq, double& apq, double& apr, double& aqr,
    double& vp0, double& vq0, double& vp1, double& vq1, double& vp2, double& vq2)
{
    // NaN/inf-safe: if apq ~ 0, selects force identity rotation.
    const double theta = (aqq - app) * 0.5 / apq;
    const double t0 = copysign(1.0, theta) / (fabs(theta) + sqrt(theta*theta + 1.0));
    const double c0 = 1.0 / sqrt(t0*t0 + 1.0);
    const double s0 = t0 * c0;
    const bool live = fabs(apq) > 1e-300;
    const double t = live ? t0 : 0.0;
    const double c = live ? c0 : 1.0;
    const double s = live ? s0 : 0.0;

    app -= t * apq;
    aqq += t * apq;
    apq  = 0.0;
    const double pr = apr, qr = aqr;
    apr = c*pr - s*qr;
    aqr = s*pr + c*qr;

    double a, bv;
    a = vp0; bv = vq0; vp0 = c*a - s*bv; vq0 = s*a + c*bv;
    a = vp1; bv = vq1; vp1 = c*a - s*bv; vq1 = s*a + c*bv;
    a = vp2; bv = vq2; vp2 = c*a - s*bv; vq2 = s*a + c*bv;
}

__global__ void svd_kernel(const float* __restrict__ stats, float* __restrict__ RT)
{
    const int b = blockIdx.x * blockDim.x + threadIdx.x;
    if (b >= NB) return;

    double s0=0,s1=0,s2=0,s3=0,s4=0,s5=0,s6=0,s7=0,s8=0,
           s9=0,s10=0,s11=0,s12=0,s13=0,s14=0;
#pragma unroll
    for (int sp = 0; sp < SPLITS; ++sp) {
        const float* st = stats + ((size_t)(b * SPLITS + sp)) * 16;
        s0  += st[0];  s1  += st[1];  s2  += st[2];
        s3  += st[3];  s4  += st[4];  s5  += st[5];
        s6  += st[6];  s7  += st[7];  s8  += st[8];
        s9  += st[9];  s10 += st[10]; s11 += st[11];
        s12 += st[12]; s13 += st[13]; s14 += st[14];
    }
    const double inv_n = 1.0 / (double)NPT;
    const double cA0 = s0*inv_n, cA1 = s1*inv_n, cA2 = s2*inv_n;
    const double cB0 = s3*inv_n, cB1 = s4*inv_n, cB2 = s5*inv_n;

    // H[i][j] = M[i][j] - N * cA_i * cB_j
    const double n_ = (double)NPT;
    const double h00 = s6  - n_*cA0*cB0, h01 = s7  - n_*cA0*cB1, h02 = s8  - n_*cA0*cB2;
    const double h10 = s9  - n_*cA1*cB0, h11 = s10 - n_*cA1*cB1, h12 = s11 - n_*cA1*cB2;
    const double h20 = s12 - n_*cA2*cB0, h21 = s13 - n_*cA2*cB1, h22 = s14 - n_*cA2*cB2;

    // A = H^T H (symmetric PSD), 6 unique elements
    double a00 = h00*h00 + h10*h10 + h20*h20;
    double a01 = h00*h01 + h10*h11 + h20*h21;
    double a02 = h00*h02 + h10*h12 + h20*h22;
    double a11 = h01*h01 + h11*h11 + h21*h21;
    double a12 = h01*h02 + h11*h12 + h21*h22;
    double a22 = h02*h02 + h12*h12 + h22*h22;

    double v00=1, v01=0, v02=0,
           v10=0, v11=1, v12=0,
           v20=0, v21=0, v22=1;

#pragma unroll
    for (int sw = 0; sw < 7; ++sw) {
        // (p,q)=(0,1), r=2
        jrot(a00, a11, a01, a02, a12,  v00, v01, v10, v11, v20, v21);
        // (p,q)=(0,2), r=1
        jrot(a00, a22, a02, a01, a12,  v00, v02, v10, v12, v20, v22);
        // (p,q)=(1,2), r=0
        jrot(a11, a22, a12, a01, a02,  v01, v02, v11, v12, v21, v22);
    }
    const double e0 = a00, e1 = a11, e2 = a22;

    // U columns: u_j = normalize(H v_j)
    const double u00 = h00*v00 + h01*v10 + h02*v20;   // u_0 components
    const double u10 = h10*v00 + h11*v10 + h12*v20;
    const double u20 = h20*v00 + h21*v10 + h22*v20;
    const double u01 = h00*v01 + h01*v11 + h02*v21;   // u_1
    const double u11 = h10*v01 + h11*v11 + h12*v21;
    const double u21 = h20*v01 + h21*v11 + h22*v21;
    const double u02 = h00*v02 + h01*v12 + h02*v22;   // u_2
    const double u12 = h10*v02 + h11*v12 + h12*v22;
    const double u22 = h20*v02 + h21*v12 + h22*v22;

    const double i0 = 1.0 / sqrt(fmax(u00*u00 + u10*u10 + u20*u20, 1e-300));
    const double i1 = 1.0 / sqrt(fmax(u01*u01 + u11*u11 + u21*u21, 1e-300));
    const double i2 = 1.0 / sqrt(fmax(u02*u02 + u12*u12 + u22*u22, 1e-300));

    const double q00 = u00*i0, q10 = u10*i0, q20 = u20*i0;
    const double q01 = u01*i1, q11 = u11*i1, q21 = u21*i1;
    const double q02 = u02*i2, q12 = u12*i2, q22 = u22*i2;

    // det(H) sign decides the Kabsch reflection fix (== sign(detU*detV))
    const double detH = h00*(h11*h22 - h12*h21)
                      - h01*(h10*h22 - h12*h20)
                      + h02*(h10*h21 - h11*h20);
    const bool flip = detH < 0.0;

    // argmin eigenvalue -> which V/U column gets the sign flip
    int m = 0; double emin = e0;
    if (e1 < emin) { m = 1; emin = e1; }
    if (e2 < emin) { m = 2; }
    const double f0 = (flip && m == 0) ? -1.0 : 1.0;
    const double f1 = (flip && m == 1) ? -1.0 : 1.0;
    const double f2 = (flip && m == 2) ? -1.0 : 1.0;

    // R[i][k] = sum_j f_j * V[i][j] * Q[k][j]
    const double R00 = f0*v00*q00 + f1*v01*q01 + f2*v02*q02;
    const double R01 = f0*v00*q10 + f1*v01*q11 + f2*v02*q12;
    const double R02 = f0*v00*q20 + f1*v01*q21 + f2*v02*q22;
    const double R10 = f0*v10*q00 + f1*v11*q01 + f2*v12*q02;
    const double R11 = f0*v10*q10 + f1*v11*q11 + f2*v12*q12;
    const double R12 = f0*v10*q20 + f1*v11*q21 + f2*v12*q22;
    const double R20 = f0*v20*q00 + f1*v21*q01 + f2*v22*q02;
    const double R21 = f0*v20*q10 + f1*v21*q11 + f2*v22*q12;
    const double R22 = f0*v20*q20 + f1*v21*q21 + f2*v22*q22;

    const double t0v = cB0 - (R00*cA0 + R01*cA1 + R02*cA2);
    const double t1v = cB1 - (R10*cA0 + R11*cA1 + R12*cA2);
    const double t2v = cB2 - (R20*cA0 + R21*cA1 + R22*cA2);

    float* o = RT + (size_t)b * 12;
    o[0] = (float)R00; o[1] = (float)R01; o[2] = (float)R02;
    o[3] = (float)R10; o[4] = (float)R11; o[5] = (float)R12;
    o[6] = (float)R20; o[7] = (float)R21; o[8] = (float)R22;
    o[9] = (float)t0v; o[10] = (float)t1v; o[11] = (float)t2v;
}

// ---------------------------------------------------------------------------
// Pass 3: clamped distance partial sums per (batch, split) block.
// pred_aligned[n,j] = sum_i pred[n,i] * R[i][j] + t[j]   (pred @ R, faithful)
// Vectorized loads: 3x float4 per 4 points.
// ---------------------------------------------------------------------------
__global__ __launch_bounds__(THREADS) void dist_kernel(
    const float* __restrict__ pred, const float* __restrict__ tru,
    const float* __restrict__ RT, float* __restrict__ partial)
{
    const int blk = blockIdx.x;
    const int b  = blk >> 2;
    const int sp = blk & 3;
    const float4* __restrict__ P4 =
        (const float4*)(pred + ((size_t)b * NPT + (size_t)sp * CHUNK) * 3);
    const float4* __restrict__ T4 =
        (const float4*)(tru  + ((size_t)b * NPT + (size_t)sp * CHUNK) * 3);
    const float* rt = RT + (size_t)b * 12;
    const float R00 = rt[0], R01 = rt[1], R02 = rt[2];
    const float R10 = rt[3], R11 = rt[4], R12 = rt[5];
    const float R20 = rt[6], R21 = rt[7], R22 = rt[8];
    const float t0 = rt[9], t1 = rt[10], t2 = rt[11];

    float acc = 0.f;

#define DISTACC(px,py,pz,tx,ty,tz)                                          \
    do {                                                                    \
        const float ax = (px)*R00 + (py)*R10 + (pz)*R20 + t0;               \
        const float ay = (px)*R01 + (py)*R11 + (pz)*R21 + t1;               \
        const float az = (px)*R02 + (py)*R12 + (pz)*R22 + t2;               \
        const float dx = ax - (tx), dy = ay - (ty), dz = az - (tz);         \
        const float d = sqrtf(dx*dx + dy*dy + dz*dz);                       \
        acc += fminf(d, CLAMPV);                                            \
    } while (0)

    for (int g = threadIdx.x; g < CHUNK / 4; g += THREADS) {
        const float4 pa = P4[3*g+0], pb = P4[3*g+1], pc = P4[3*g+2];
        const float4 ta = T4[3*g+0], tb = T4[3*g+1], tc = T4[3*g+2];
        DISTACC(pa.x, pa.y, pa.z,  ta.x, ta.y, ta.z);
        DISTACC(pa.w, pb.x, pb.y,  ta.w, tb.x, tb.y);
        DISTACC(pb.z, pb.w, pc.x,  tb.z, tb.w, tc.x);
        DISTACC(pc.y, pc.z, pc.w,  tc.y, tc.z, tc.w);
    }
#undef DISTACC

    for (int off = 32; off > 0; off >>= 1)
        acc += __shfl_down(acc, off, 64);
    __shared__ float smem[THREADS/64];
    const int wave = threadIdx.x >> 6, lane = threadIdx.x & 63;
    if (lane == 0) smem[wave] = acc;
    __syncthreads();
    if (threadIdx.x == 0) {
        float s = 0.f;
#pragma unroll
        for (int w = 0; w < THREADS/64; ++w) s += smem[w];
        partial[blk] = s;
    }
}

// ---------------------------------------------------------------------------
// Pass 4: reduce NB*SPLITS partials -> global mean
// ---------------------------------------------------------------------------
__global__ __launch_bounds__(THREADS) void finalize_kernel(
    const float* __restrict__ partial, float* __restrict__ out)
{
    float acc = 0.f;
    for (int i = threadIdx.x; i < NB * SPLITS; i += THREADS) acc += partial[i];
    for (int off = 32; off > 0; off >>= 1)
        acc += __shfl_down(acc, off, 64);
    __shared__ float smem[THREADS/64];
    const int wave = threadIdx.x >> 6, lane = threadIdx.x & 63;
    if (lane == 0) smem[wave] = acc;
    __syncthreads();
    if (threadIdx.x == 0) {
        float s = 0.f;
#pragma unroll
        for (int w = 0; w < THREADS/64; ++w) s += smem[w];
        out[0] = s / 2097152.0f;   // B*N = 256*8192
    }
}

extern "C" void kernel_launch(void* const* d_in, const int* in_sizes, int n_in,
                              void* d_out, int out_size, void* d_ws, size_t ws_size,
                              hipStream_t stream)
{
    // inputs: [0] pred_frames (unused), [1] true_frames (unused),
    //         [2] pred_pos [256,8192,3] f32, [3] true_pos [256,8192,3] f32
    const float* pred_pos = (const float*)d_in[2];
    const float* true_pos = (const float*)d_in[3];
    float* out = (float*)d_out;

    float* ws      = (float*)d_ws;
    float* stats   = ws;                            // NB*SPLITS*16 = 16384 floats
    float* RT      = ws + (size_t)NB * SPLITS * 16; // NB*12 = 3072 floats
    float* partial = RT + (size_t)NB * 12;          // NB*SPLITS = 1024 floats

    cov_kernel<<<NB * SPLITS, THREADS, 0, stream>>>(pred_pos, true_pos, stats);
    svd_kernel<<<1, NB, 0, stream>>>(stats, RT);
    dist_kernel<<<NB * SPLITS, THREADS, 0, stream>>>(pred_pos, true_pos, RT, partial);
    finalize_kernel<<<1, THREADS, 0, stream>>>(partial, out);
}